// Round 9
// baseline (301749.536 us; speedup 1.0000x reference)
//
#include <hip/hip_runtime.h>
#include <math.h>

// ControlledNODE: sequential RK4 scan, T=65536 steps.
// Round-9 = round-8 (2 waves, packed v_pk_fma_f32, 2 full barriers/stage,
// shallow pb2 reduce) + two changes:
//  * amdgpu_waves_per_eu(1,1): allocator budget = full 512-reg unified file
//    per wave -> all 200 weight VGPRs arch-resident, no AGPR parking, no
//    v_accvgpr_read per FMA (gfx950 VALU cannot read AGPR sources; round 5).
//  * Own-half-first L2: each wave first accumulates the z1 half IT produced
//    (wave-local, in-order DS), the full barrier B1 sits between the halves,
//    so cross-wave z1 latency hides under 32 pk_fma of useful work.
// Barrier map: B1 (mid-L2, z1 cross-wave), B3 (pb2 cross-wave) full;
// z1-own/z2/xbuf transitions are wave-local wave_barrier()s (validated r7/r8).

constexpr int T_STEPS = 65536;
constexpr int HD  = 32;   // state dim
constexpr int HID = 128;  // hidden dim

typedef float v2f __attribute__((ext_vector_type(2)));

__device__ __forceinline__ v2f fma2(v2f a, v2f b, v2f c) {
    return __builtin_elementwise_fma(a, b, c);   // -> v_pk_fma_f32
}

__device__ __forceinline__ float silu_f(float a) {
    // a * sigmoid(a); exp overflow -> inf -> a/inf = 0 (correct limit)
    return a / (1.0f + __expf(-a));
}

// Workgroup barrier without vmcnt drain.
__device__ __forceinline__ void wg_barrier() {
    asm volatile("s_waitcnt lgkmcnt(0)" ::: "memory");
    __builtin_amdgcn_s_barrier();
    asm volatile("" ::: "memory");
}

__global__ __launch_bounds__(128)
__attribute__((amdgpu_waves_per_eu(1, 1)))
void node_scan(const float* __restrict__ U,
               const float* __restrict__ h0,
               const float* __restrict__ W1, const float* __restrict__ b1,
               const float* __restrict__ W2, const float* __restrict__ b2,
               const float* __restrict__ W3, const float* __restrict__ b3,
               const float* __restrict__ Wd, const float* __restrict__ bd,
               const float* __restrict__ Wt, const float* __restrict__ bt,
               const float* __restrict__ Wc, const float* __restrict__ bc,
               float* __restrict__ out)
{
    const int tid = threadIdx.x;    // 0..127
    const int j   = tid;            // hidden unit owned (L1/L2)
    const int m   = tid & 31;       // state/drift index
    const int seg = tid >> 5;       // L3 K-segment 0..3 (wave-local pairs)
    const int wv  = tid >> 6;       // wave id 0/1
    // Tell the compiler wv is wave-uniform -> scalar branches, no exec juggling.
    const int wvu = __builtin_amdgcn_readfirstlane(wv);

    __shared__ __align__(16) float xbuf[HD];     // RK-stage state input
    __shared__ __align__(16) float z1buf[HID];
    __shared__ __align__(16) float z2buf[HID];
    __shared__ __align__(16) float pb2[64];      // per-wave K-half drift partials

    // ---- one-time: weights into registers as packed pairs ----
    v2f w1p[20];                                  // [0..15]=x part, [16..19]=u part
#pragma unroll
    for (int i = 0; i < 20; ++i) {
        w1p[i].x = W1[(2 * i) * HID + j];
        w1p[i].y = W1[(2 * i + 1) * HID + j];
    }
    const float b1r = b1[j];

    v2f w2p[64];                                  // [0..31]=k<64, [32..63]=k>=64
#pragma unroll
    for (int i = 0; i < 64; ++i) {
        w2p[i].x = W2[(2 * i) * HID + j];
        w2p[i].y = W2[(2 * i + 1) * HID + j];
    }
    const float b2r = b2[j];

    v2f w3p[16];                                  // seg slice, packed pairs
#pragma unroll
    for (int i = 0; i < 16; ++i) {
        w3p[i].x = W3[(seg * 32 + 2 * i) * HD + m];
        w3p[i].y = W3[(seg * 32 + 2 * i + 1) * HD + m];
    }
    const float b3r = b3[m];

    // heads: wave0 reduces d and c, wave1 reduces t
    const float whr = (wvu == 0) ? Wd[m] : Wt[m];
    const float wcr = Wc[m];
    const float bd0 = bd[0], bt0 = bt[0], bc0 = bc[0];

    float hm   = h0[m];    // replicated in all 128 lanes
    float xm   = hm;       // current stage input state x[m]
    float kacc = 0.0f;

    const float DT  = 5.0f / 60.0f;
    const float HDT = 0.5f * DT;
    const float W6  = DT / 6.0f;

    // u double-buffer (same addr all lanes -> broadcast, L2-cached)
    float4 ua = *(const float4*)(U);
    float4 ub = *(const float4*)(U + 4);

    xbuf[m] = xm;                    // all lanes, identical values: benign
    wg_barrier();

    // L2 inner-chunk macro: one float4 of z1 against the matching w2p pair.
#define L2_CHUNK(i4)                                           \
    {                                                          \
        const float4 v = z1v[i4];                              \
        v2f lo; lo.x = v.x; lo.y = v.y;                        \
        v2f hi; hi.x = v.z; hi.y = v.w;                        \
        if ((i4) & 1) {                                        \
            c2 = fma2(lo, w2p[2 * (i4)],     c2);              \
            c3 = fma2(hi, w2p[2 * (i4) + 1], c3);              \
        } else {                                               \
            c0 = fma2(lo, w2p[2 * (i4)],     c0);              \
            c1 = fma2(hi, w2p[2 * (i4) + 1], c1);              \
        }                                                      \
    }

    for (int t = 0; t < T_STEPS; ++t) {
        // prefetch next step's u (no vmcnt drain at barriers -> in flight)
        const int tn = (t + 1 < T_STEPS) ? (t + 1) : t;
        const float4 na = *(const float4*)(U + tn * 8);
        const float4 nb = *(const float4*)(U + tn * 8 + 4);

        // ---- heads from current h (pre-update): pure reg + shuffle ----
        {
            float p  = hm * whr;
            float pc = hm * wcr;
            p += __shfl_xor(p, 16);  pc += __shfl_xor(pc, 16);
            p += __shfl_xor(p, 8);   pc += __shfl_xor(pc, 8);
            p += __shfl_xor(p, 4);   pc += __shfl_xor(pc, 4);
            p += __shfl_xor(p, 2);   pc += __shfl_xor(pc, 2);
            p += __shfl_xor(p, 1);   pc += __shfl_xor(pc, 1);
            if (tid == 0)  { out[t] = p + bd0; out[2 * T_STEPS + t] = pc + bc0; }
            if (tid == 64) { out[T_STEPS + t] = p + bt0; }
        }

        // ---- u-projection: constant across the 4 RK stages, hoisted ----
        float upj;
        {
            v2f u0; u0.x = ua.x; u0.y = ua.y;
            v2f u1; u1.x = ua.z; u1.y = ua.w;
            v2f u2; u2.x = ub.x; u2.y = ub.y;
            v2f u3; u3.x = ub.z; u3.y = ub.w;
            v2f up = {b1r, 0.0f};
            up = fma2(u0, w1p[16], up);
            up = fma2(u1, w1p[17], up);
            up = fma2(u2, w1p[18], up);
            up = fma2(u3, w1p[19], up);
            upj = up.x + up.y;
        }

#pragma unroll
        for (int st = 0; st < 4; ++st) {
            // ---- L1: z1[j] = silu([x,u] @ W1 + b1), packed ----
            v2f a0 = {upj, 0.0f}, a1 = {0.0f, 0.0f};
            const float4* xv = (const float4*)xbuf;
#pragma unroll
            for (int i4 = 0; i4 < 8; ++i4) {
                const float4 v = xv[i4];            // broadcast read
                v2f lo; lo.x = v.x; lo.y = v.y;
                v2f hi; hi.x = v.z; hi.y = v.w;
                a0 = fma2(lo, w1p[2 * i4],     a0);
                a1 = fma2(hi, w1p[2 * i4 + 1], a1);
            }
            const v2f as = a0 + a1;
            z1buf[j] = silu_f(as.x + as.y);
            __builtin_amdgcn_wave_barrier();         // own z1 write < own reads

            // ---- L2 own half: the z1 half this wave just produced ----
            v2f c0 = {b2r, 0.0f}, c1 = {0.0f, 0.0f};
            v2f c2 = {0.0f, 0.0f}, c3 = {0.0f, 0.0f};
            const float4* z1v = (const float4*)z1buf;
            if (wvu == 0) {
#pragma unroll
                for (int i4 = 0; i4 < 16; ++i4) L2_CHUNK(i4);
            } else {
#pragma unroll
                for (int i4 = 16; i4 < 32; ++i4) L2_CHUNK(i4);
            }
            wg_barrier();                            // B1: other wave's z1 now visible

            // ---- L2 other half + z2 write ----
            if (wvu == 0) {
#pragma unroll
                for (int i4 = 16; i4 < 32; ++i4) L2_CHUNK(i4);
            } else {
#pragma unroll
                for (int i4 = 0; i4 < 16; ++i4) L2_CHUNK(i4);
            }
            const v2f cs = (c0 + c1) + (c2 + c3);
            z2buf[j] = silu_f(cs.x + cs.y);
            __builtin_amdgcn_wave_barrier();         // wave-local: z2 -> L3

            // ---- L3 partial: drift[m] over segment seg (own wave's z2) ----
            v2f p0 = {0.0f, 0.0f}, p1 = {0.0f, 0.0f};
            const float4* z2v = (const float4*)(z2buf + seg * 32);
#pragma unroll
            for (int i4 = 0; i4 < 8; ++i4) {
                const float4 v = z2v[i4];           // 2 addr groups: free
                v2f lo; lo.x = v.x; lo.y = v.y;
                v2f hi; hi.x = v.z; hi.y = v.w;
                p0 = fma2(lo, w3p[2 * i4],     p0);
                p1 = fma2(hi, w3p[2 * i4 + 1], p1);
            }
            const v2f ps = p0 + p1;
            float pr = ps.x + ps.y;
            pr += __shfl_xor(pr, 32);   // combine seg pair within wave
            pb2[wv * 32 + m] = pr;      // 2 lanes/addr, same value: benign
            wg_barrier();                            // B3: pb2 crosses waves

            // ---- RK combine: ALL lanes redundantly (hm replicated) ----
            {
                const float drift = (pb2[m] + pb2[m + 32]) + b3r;
                const float k = 0.02f * drift - 0.1f * xm;
                if (st == 0)      { kacc = k;           xm = hm + HDT * k; }
                else if (st == 1) { kacc += 2.0f * k;   xm = hm + HDT * k; }
                else if (st == 2) { kacc += 2.0f * k;   xm = hm + DT  * k; }
                else {
                    kacc += k;
                    float hn = hm + W6 * kacc;
                    if (!isfinite(hn)) hn = 0.0f;        // nan_to_num BEFORE tanh
                    hn = tanhf(hn);
                    hn = fminf(fmaxf(hn, -5.0f), 5.0f);  // fidelity no-op after tanh
                    hm = hn; xm = hn;
                }
                xbuf[m] = xm;   // all lanes, identical values: benign race
            }
            __builtin_amdgcn_wave_barrier();         // wave-local: xbuf -> L1
        }
        ua = na; ub = nb;
    }
#undef L2_CHUNK

    if (tid < HD) out[3 * T_STEPS + tid] = hm;
}

extern "C" void kernel_launch(void* const* d_in, const int* in_sizes, int n_in,
                              void* d_out, int out_size, void* d_ws, size_t ws_size,
                              hipStream_t stream) {
    const float* U  = (const float*)d_in[0];
    const float* h0 = (const float*)d_in[1];
    const float* W1 = (const float*)d_in[2];
    const float* b1 = (const float*)d_in[3];
    const float* W2 = (const float*)d_in[4];
    const float* b2 = (const float*)d_in[5];
    const float* W3 = (const float*)d_in[6];
    const float* b3 = (const float*)d_in[7];
    const float* Wd = (const float*)d_in[8];
    const float* bd = (const float*)d_in[9];
    const float* Wt = (const float*)d_in[10];
    const float* bt = (const float*)d_in[11];
    const float* Wc = (const float*)d_in[12];
    const float* bc = (const float*)d_in[13];
    float* out = (float*)d_out;

    node_scan<<<1, 128, 0, stream>>>(U, h0, W1, b1, W2, b2, W3, b3,
                                     Wd, bd, Wt, bt, Wc, bc, out);
}

// Round 10
// 235910.986 us; speedup vs baseline: 1.2791x; 1.2791x over previous
//
#include <hip/hip_runtime.h>
#include <math.h>

// ControlledNODE: sequential RK4 scan, T=65536 steps.
// Round-10 = round-8 skeleton (2 waves, v_pk_fma_f32, 2 full barriers/stage,
// ~200 weight floats/lane -> VGPR ~128 w/ AGPR parking) with SPLIT-K L2:
//  * Thread (l, wv) computes TWO z2 outputs (l, l+64) over its wave's K-half
//    k in [wv*64, wv*64+64): z1 reads 32 -> 16 b128/wave/stage, and the z1
//    dependency becomes WAVE-LOCAL (wave wv produced exactly that half).
//  * Cross-wave sync moves to a 2-float partial exchange (pex): b64 write,
//    full barrier B1', b64 read. Full-barrier count per stage unchanged (2).
//  * z2 computed replicated in both waves, written in SLOT order (slot 2l ->
//    unit l, 2l+1 -> unit l+64) as one b64; L3 reads stay wave-local 8 b128
//    with W3 loaded in slot order. pb2 paired so RK reads one b64.
// Hazards: pex WAW across stages separated by B3; z1/z2/xbuf reads are
// own-wave (in-order DS); xbuf WAR separated by B1'+B3 (validated r7/r8).

constexpr int T_STEPS = 65536;
constexpr int HD  = 32;   // state dim
constexpr int HID = 128;  // hidden dim

typedef float v2f __attribute__((ext_vector_type(2)));

__device__ __forceinline__ v2f fma2(v2f a, v2f b, v2f c) {
    return __builtin_elementwise_fma(a, b, c);   // -> v_pk_fma_f32
}

__device__ __forceinline__ float silu_f(float a) {
    // a * sigmoid(a); exp overflow -> inf -> a/inf = 0 (correct limit)
    return a / (1.0f + __expf(-a));
}

// Workgroup barrier without vmcnt drain.
__device__ __forceinline__ void wg_barrier() {
    asm volatile("s_waitcnt lgkmcnt(0)" ::: "memory");
    __builtin_amdgcn_s_barrier();
    asm volatile("" ::: "memory");
}

__global__ __launch_bounds__(128, 1)
void node_scan(const float* __restrict__ U,
               const float* __restrict__ h0,
               const float* __restrict__ W1, const float* __restrict__ b1,
               const float* __restrict__ W2, const float* __restrict__ b2,
               const float* __restrict__ W3, const float* __restrict__ b3,
               const float* __restrict__ Wd, const float* __restrict__ bd,
               const float* __restrict__ Wt, const float* __restrict__ bt,
               const float* __restrict__ Wc, const float* __restrict__ bc,
               float* __restrict__ out)
{
    const int tid = threadIdx.x;    // 0..127
    const int j   = tid;            // L1 output unit
    const int l   = tid & 63;       // lane within wave; L2 outputs l, l+64
    const int m   = tid & 31;       // state/drift index
    const int seg = tid >> 5;       // L3 slot-segment 0..3
    const int wv  = tid >> 6;       // wave id 0/1; L2 K-half base = wv*64

    __shared__ __align__(16) float xbuf[HD];       // RK-stage state input
    __shared__ __align__(16) float z1buf[HID];     // unit order
    __shared__ __align__(16) float z2slot[HID];    // slot 2l=unit l, 2l+1=unit l+64
    __shared__ __align__(16) float pex[2 * HID];   // L2 partials, float2 per lane
    __shared__ __align__(16) float pb2[64];        // L3 partials, paired by wave

    // ---- one-time: weights into registers as packed pairs ----
    v2f w1p[20];                                  // [0..15]=x part, [16..19]=u part
#pragma unroll
    for (int i = 0; i < 20; ++i) {
        w1p[i].x = W1[(2 * i) * HID + j];
        w1p[i].y = W1[(2 * i + 1) * HID + j];
    }
    const float b1r = b1[j];

    // W2 slices for outputs l and l+64 over K-half [wv*64, wv*64+64)
    v2f w2a[32], w2b[32];                         // k-pairs
#pragma unroll
    for (int kp = 0; kp < 32; ++kp) {
        const int k = wv * 64 + 2 * kp;
        w2a[kp].x = W2[k * HID + l];
        w2a[kp].y = W2[(k + 1) * HID + l];
        w2b[kp].x = W2[k * HID + l + 64];
        w2b[kp].y = W2[(k + 1) * HID + l + 64];
    }
    const float b2a = b2[l], b2b = b2[l + 64];

    // W3 slice in SLOT order: w3p[i] covers slots (seg*32+2i, seg*32+2i+1)
    // slot s -> unit (s>>1) + (s&1)*64; here: units seg*16+i and seg*16+i+64
    v2f w3p[16];
#pragma unroll
    for (int i = 0; i < 16; ++i) {
        w3p[i].x = W3[(seg * 16 + i) * HD + m];
        w3p[i].y = W3[(seg * 16 + i + 64) * HD + m];
    }
    const float b3r = b3[m];

    // heads: wave0 reduces d and c, wave1 reduces t
    const float whr = (wv == 0) ? Wd[m] : Wt[m];
    const float wcr = Wc[m];
    const float bd0 = bd[0], bt0 = bt[0], bc0 = bc[0];

    float hm   = h0[m];    // replicated in all 128 lanes
    float xm   = hm;       // current stage input state x[m]
    float kacc = 0.0f;

    const float DT  = 5.0f / 60.0f;
    const float HDT = 0.5f * DT;
    const float W6  = DT / 6.0f;

    // u double-buffer (same addr all lanes -> broadcast, L2-cached)
    float4 ua = *(const float4*)(U);
    float4 ub = *(const float4*)(U + 4);

    xbuf[m] = xm;                    // all lanes, identical values: benign
    wg_barrier();

    for (int t = 0; t < T_STEPS; ++t) {
        // prefetch next step's u (no vmcnt drain at barriers -> in flight)
        const int tn = (t + 1 < T_STEPS) ? (t + 1) : t;
        const float4 na = *(const float4*)(U + tn * 8);
        const float4 nb = *(const float4*)(U + tn * 8 + 4);

        // ---- heads from current h (pre-update): pure reg + shuffle ----
        {
            float p  = hm * whr;
            float pc = hm * wcr;
            p += __shfl_xor(p, 16);  pc += __shfl_xor(pc, 16);
            p += __shfl_xor(p, 8);   pc += __shfl_xor(pc, 8);
            p += __shfl_xor(p, 4);   pc += __shfl_xor(pc, 4);
            p += __shfl_xor(p, 2);   pc += __shfl_xor(pc, 2);
            p += __shfl_xor(p, 1);   pc += __shfl_xor(pc, 1);
            if (tid == 0)  { out[t] = p + bd0; out[2 * T_STEPS + t] = pc + bc0; }
            if (tid == 64) { out[T_STEPS + t] = p + bt0; }
        }

        // ---- u-projection: constant across the 4 RK stages, hoisted ----
        float upj;
        {
            v2f u0; u0.x = ua.x; u0.y = ua.y;
            v2f u1; u1.x = ua.z; u1.y = ua.w;
            v2f u2; u2.x = ub.x; u2.y = ub.y;
            v2f u3; u3.x = ub.z; u3.y = ub.w;
            v2f up = {b1r, 0.0f};
            up = fma2(u0, w1p[16], up);
            up = fma2(u1, w1p[17], up);
            up = fma2(u2, w1p[18], up);
            up = fma2(u3, w1p[19], up);
            upj = up.x + up.y;
        }

#pragma unroll
        for (int st = 0; st < 4; ++st) {
            // ---- L1: z1[j] = silu([x,u] @ W1 + b1), packed ----
            v2f a0 = {upj, 0.0f}, a1 = {0.0f, 0.0f};
            const float4* xv = (const float4*)xbuf;
#pragma unroll
            for (int i4 = 0; i4 < 8; ++i4) {
                const float4 v = xv[i4];            // broadcast read
                v2f lo; lo.x = v.x; lo.y = v.y;
                v2f hi; hi.x = v.z; hi.y = v.w;
                a0 = fma2(lo, w1p[2 * i4],     a0);
                a1 = fma2(hi, w1p[2 * i4 + 1], a1);
            }
            const v2f as = a0 + a1;
            z1buf[j] = silu_f(as.x + as.y);
            __builtin_amdgcn_wave_barrier();         // own z1 half < own reads

            // ---- L2 split-K: outputs (l, l+64) over own wave's z1 half ----
            v2f aA0 = {0.0f, 0.0f}, aA1 = {0.0f, 0.0f};
            v2f aB0 = {0.0f, 0.0f}, aB1 = {0.0f, 0.0f};
            const float4* z1v = (const float4*)(z1buf + wv * 64);
#pragma unroll
            for (int i4 = 0; i4 < 16; ++i4) {
                const float4 v = z1v[i4];           // broadcast read (own half)
                v2f lo; lo.x = v.x; lo.y = v.y;
                v2f hi; hi.x = v.z; hi.y = v.w;
                aA0 = fma2(lo, w2a[2 * i4],     aA0);
                aA1 = fma2(hi, w2a[2 * i4 + 1], aA1);
                aB0 = fma2(lo, w2b[2 * i4],     aB0);
                aB1 = fma2(hi, w2b[2 * i4 + 1], aB1);
            }
            const v2f sA = aA0 + aA1;
            const v2f sB = aB0 + aB1;
            float2 mine;
            mine.x = sA.x + sA.y;                   // partial for output l
            mine.y = sB.x + sB.y;                   // partial for output l+64
            ((float2*)pex)[wv * 64 + l] = mine;     // b64 write
            wg_barrier();                            // B1': pex crosses waves

            const float2 po = ((const float2*)pex)[(1 ^ wv) * 64 + l];
            const float z2A = silu_f(mine.x + po.x + b2a);
            const float z2B = silu_f(mine.y + po.y + b2b);
            float2 zs; zs.x = z2A; zs.y = z2B;
            ((float2*)z2slot)[l] = zs;              // slot order; replicated: benign
            __builtin_amdgcn_wave_barrier();         // own z2 writes < own L3 reads

            // ---- L3 partial: drift[m] over slot segment seg (own wave) ----
            v2f p0 = {0.0f, 0.0f}, p1 = {0.0f, 0.0f};
            const float4* z2v = (const float4*)(z2slot + seg * 32);
#pragma unroll
            for (int i4 = 0; i4 < 8; ++i4) {
                const float4 v = z2v[i4];           // 2 addr groups: free
                v2f lo; lo.x = v.x; lo.y = v.y;
                v2f hi; hi.x = v.z; hi.y = v.w;
                p0 = fma2(lo, w3p[2 * i4],     p0);
                p1 = fma2(hi, w3p[2 * i4 + 1], p1);
            }
            const v2f ps = p0 + p1;
            float pr = ps.x + ps.y;
            pr += __shfl_xor(pr, 32);   // combine seg pair within wave
            pb2[2 * m + wv] = pr;       // paired layout; 2 lanes/addr same value
            wg_barrier();                            // B3: pb2 crosses waves

            // ---- RK combine: ALL lanes redundantly (hm replicated) ----
            {
                const float2 pp = ((const float2*)pb2)[m];   // b64 read
                const float drift = (pp.x + pp.y) + b3r;
                const float k = 0.02f * drift - 0.1f * xm;
                if (st == 0)      { kacc = k;           xm = hm + HDT * k; }
                else if (st == 1) { kacc += 2.0f * k;   xm = hm + HDT * k; }
                else if (st == 2) { kacc += 2.0f * k;   xm = hm + DT  * k; }
                else {
                    kacc += k;
                    float hn = hm + W6 * kacc;
                    if (!isfinite(hn)) hn = 0.0f;        // nan_to_num BEFORE tanh
                    hn = tanhf(hn);
                    hn = fminf(fmaxf(hn, -5.0f), 5.0f);  // fidelity no-op after tanh
                    hm = hn; xm = hn;
                }
                xbuf[m] = xm;   // all lanes, identical values: benign race
            }
            __builtin_amdgcn_wave_barrier();         // wave-local: xbuf -> L1
        }
        ua = na; ub = nb;
    }

    if (tid < HD) out[3 * T_STEPS + tid] = hm;
}

extern "C" void kernel_launch(void* const* d_in, const int* in_sizes, int n_in,
                              void* d_out, int out_size, void* d_ws, size_t ws_size,
                              hipStream_t stream) {
    const float* U  = (const float*)d_in[0];
    const float* h0 = (const float*)d_in[1];
    const float* W1 = (const float*)d_in[2];
    const float* b1 = (const float*)d_in[3];
    const float* W2 = (const float*)d_in[4];
    const float* b2 = (const float*)d_in[5];
    const float* W3 = (const float*)d_in[6];
    const float* b3 = (const float*)d_in[7];
    const float* Wd = (const float*)d_in[8];
    const float* bd = (const float*)d_in[9];
    const float* Wt = (const float*)d_in[10];
    const float* bt = (const float*)d_in[11];
    const float* Wc = (const float*)d_in[12];
    const float* bc = (const float*)d_in[13];
    float* out = (float*)d_out;

    node_scan<<<1, 128, 0, stream>>>(U, h0, W1, b1, W2, b2, W3, b3,
                                     Wd, bd, Wt, bt, Wc, bc, out);
}